// Round 6
// baseline (61.170 us; speedup 1.0000x reference)
//
#include <hip/hip_runtime.h>

#define V 64
#define W 5
#define G 80
#define O 80
#define NROT 16
#define GPAD 96
#define NR 5
#define NT 16
#define VP 32
#define T2STRIDE (NT * 20 + 12)   // u32 per vp row: 16B-aligned, bank-staggered
#define EPSV 1e-5f
#define NLOG2E (-1.4426950408889634f)

using bf16x8 = __attribute__((ext_vector_type(8))) short;
using f32x4  = __attribute__((ext_vector_type(4))) float;
using h2     = __attribute__((ext_vector_type(2))) _Float16;

__device__ __forceinline__ unsigned short f2bf(float x) {
    unsigned u = __float_as_uint(x);
    unsigned r = (u + 0x7FFFu + ((u >> 16) & 1u)) >> 16;   // RNE
    return (unsigned short)r;
}
__device__ __forceinline__ unsigned pkrtz(float a, float b) {
    auto r = __builtin_amdgcn_cvt_pkrtz(a, b);             // half2, RTZ
    return __builtin_bit_cast(unsigned, r);
}
__device__ __forceinline__ h2 u2h(unsigned u) {
    return __builtin_bit_cast(h2, u);
}
#if __has_builtin(__builtin_amdgcn_fdot2)
#define FDOT2(a, b, c) __builtin_amdgcn_fdot2((a), (b), (c), false)
#else
#define FDOT2(a, b, c) ((float)(a)[0] * (float)(b)[0] + (float)(a)[1] * (float)(b)[1] + (c))
#endif

// ============================================================================
// Pack Wc into bf16 B-frags for mfma_f32_16x16x32_bf16 (proven in R4).
// ============================================================================
__global__ __launch_bounds__(64) void pack_wc_kernel(
    const float* __restrict__ Wc, unsigned short* __restrict__ wsB)
{
    const int f = blockIdx.x, l = threadIdx.x;
    const int w = f / 15, r = f % 15, ks = r / 5, nt = r % 5;
    const int g0 = ks * 32 + ((l >> 4) << 3);
    const int o  = nt * 16 + (l & 15);
    unsigned short v[8];
    #pragma unroll
    for (int i = 0; i < 8; ++i) {
        int g = g0 + i;
        v[i] = (g < G) ? f2bf(Wc[(w * G + g) * O + o]) : (unsigned short)0;
    }
    *(uint4*)(wsB + ((size_t)f * 64 + l) * 8) = *(const uint4*)v;
}

// ============================================================================
// Fused kernel: one block per point, 320 threads = 5 waves.
// Fast path (meshgrid-uniform params): e[v,g,k] = R[r,v]*T[t,v,k], fp16
// packed pairs over v, accumulation via v_dot2_f32_f16.
// ============================================================================
__global__ __launch_bounds__(320) void conv_kernel(
    const float* __restrict__ feat,      // [NP][V][W]
    const float* __restrict__ rho,       // [NP][V]
    const float* __restrict__ theta,     // [NP][V]
    const float* __restrict__ mask,      // [NP][V]
    const float* __restrict__ mu_rho,    // [W][G]
    const float* __restrict__ mu_theta,  // [W][G]
    const float* __restrict__ sig_rho,   // [W][G]
    const float* __restrict__ sig_theta, // [W][G]
    const unsigned short* __restrict__ wsB,  // packed bf16 Wc B-frags
    const float* __restrict__ bc,        // [W][O]
    float* __restrict__ out)             // [NP][W][O]
{
    __shared__ float s_pt[V][8];                    // f0..f4, rho, mrk, theta
    __shared__ unsigned s_T2[VP][T2STRIDE];         // half2 T pairs [vp][t*20+k]
    __shared__ unsigned s_R2[VP][8];                // half2 R' pairs [vp][r]
    __shared__ unsigned s_f2[VP][8];                // half2 feat pairs [vp][w]
    __shared__ float s_arg[NR][V];                  // raw rho-args
    __shared__ float s_shift[8];                    // per-r exponent shift
    __shared__ float s_sre[8];                      // per-r EPSV * 2^shift
    __shared__ unsigned short s_descT[W][NROT][GPAD];
    __shared__ float s_red[W][64];

    const int tid = threadIdx.x;
    const int p = blockIdx.x;
    const int g = tid % G;   // 0..79
    const int j = tid / G;   // 0..3 (k-quad)

    // ---- stage 1: stage point data; zero descT g-pad ----
    if (tid < V * W) {
        int v = tid / W, w = tid % W;
        s_pt[v][w] = feat[p * V * W + tid];
    }
    if (tid < V) {
        s_pt[tid][5] = rho[p * V + tid];
        s_pt[tid][6] = (mask[p * V + tid] != 0.0f) ? 0.0f : -1e30f;
        s_pt[tid][7] = theta[p * V + tid];
    }
    for (int i = tid; i < W * NROT * 8; i += 320) {
        int row = i >> 3, col = 40 + (i & 7);
        ((unsigned*)s_descT)[row * 48 + col] = 0u;
    }

    // uniformity + meshgrid check (8 conditions over all threads)
    const int wchk = 1 + j;
    const int gr = (g >> 4) << 4;   // row-base for rho params
    const int gt = g & 15;          // col-base for theta params
    int pred = (mu_rho  [wchk * G + g] == mu_rho  [g]) &&
               (mu_theta[wchk * G + g] == mu_theta[g]) &&
               (sig_rho [wchk * G + g] == sig_rho [g]) &&
               (sig_theta[wchk * G + g] == sig_theta[g]) &&
               (mu_rho  [g] == mu_rho  [gr]) &&
               (sig_rho [g] == sig_rho [gr]) &&
               (mu_theta[g] == mu_theta[gt]) &&
               (sig_theta[g] == sig_theta[gt]);
    const int uni = __syncthreads_and(pred);

    const float kstep = 0.39269908169872414f;      // 2*pi/16
    const float two_pi = 6.283185307179586f;
    const float inv_two_pi = 0.15915494309189535f;

    if (uni) {
        // ---- build raw rho-args: thread -> (r = tid>>6, v = tid&63) ----
        {
            int r = tid >> 6, v = tid & 63;
            float mu_r = mu_rho[r * 16];
            float srr  = sig_rho[r * 16];
            float c_r  = NLOG2E / (srr * srr + EPSV);
            float dr = s_pt[v][5] - mu_r;
            s_arg[r][v] = fmaf(dr * dr, c_r, s_pt[v][6]);   // mask folded
        }
        __syncthreads();

        // ---- per-r shift reduce (5 lanes) || T-table build (all) ----
        if (tid < NR) {
            float m = -3.0e38f;
            #pragma unroll 8
            for (int v = 0; v < V; ++v) m = fmaxf(m, s_arg[tid][v]);
            float s = fminf(-m, 60.0f);                     // arg <= 0 -> s >= 0
            s_shift[tid] = s;
            s_sre[tid]   = EPSV * __builtin_amdgcn_exp2f(s);
        }
        for (int i = tid; i < NT * VP; i += 320) {
            int t = i >> 5, vp = i & 31;
            float th0 = s_pt[2 * vp][7], th1 = s_pt[2 * vp + 1][7];
            float mu_t = mu_theta[t];
            float stt  = sig_theta[t];
            float c_t  = NLOG2E / (stt * stt + EPSV);
            unsigned rowv[16];
            #pragma unroll
            for (int k = 0; k < 16; ++k) {
                float x0 = th0 + (float)k * kstep;
                x0 -= floorf(x0 * inv_two_pi) * two_pi;
                float d0 = x0 - mu_t;
                float e0 = __builtin_amdgcn_exp2f(c_t * d0 * d0);
                float x1 = th1 + (float)k * kstep;
                x1 -= floorf(x1 * inv_two_pi) * two_pi;
                float d1 = x1 - mu_t;
                float e1 = __builtin_amdgcn_exp2f(c_t * d1 * d1);
                rowv[k] = pkrtz(e0, e1);
            }
            uint4* dst = (uint4*)&s_T2[vp][t * 20];
            dst[0] = make_uint4(rowv[0], rowv[1], rowv[2], rowv[3]);
            dst[1] = make_uint4(rowv[4], rowv[5], rowv[6], rowv[7]);
            dst[2] = make_uint4(rowv[8], rowv[9], rowv[10], rowv[11]);
            dst[3] = make_uint4(rowv[12], rowv[13], rowv[14], rowv[15]);
        }
        __syncthreads();

        // ---- build R' pairs (160 thr) and feat pairs (160 thr) ----
        if (tid < 160) {
            int vp = tid & 31, r = tid >> 5;                // r 0..4
            float s = s_shift[r];
            float e0 = __builtin_amdgcn_exp2f(s_arg[r][2 * vp] + s);
            float e1 = __builtin_amdgcn_exp2f(s_arg[r][2 * vp + 1] + s);
            s_R2[vp][r] = pkrtz(e0, e1);
        } else {
            int i = tid - 160, vp = i & 31, w = i >> 5;     // w 0..4
            s_f2[vp][w] = pkrtz(s_pt[2 * vp][w], s_pt[2 * vp + 1][w]);
        }
        __syncthreads();

        // ---- stage 2 main: thread (g,j); r=g>>4, t=g&15; 4 k per thread ----
        {
            const int r = g >> 4, t = g & 15;
            float den[4] = {0.f, 0.f, 0.f, 0.f};
            float num[5][4];
            #pragma unroll
            for (int w = 0; w < W; ++w)
                #pragma unroll
                for (int kk = 0; kk < 4; ++kk) num[w][kk] = 0.f;
            h2 one2 = {(_Float16)1.0f, (_Float16)1.0f};

            #pragma unroll 2
            for (int vp = 0; vp < VP; ++vp) {
                h2 rr = u2h(s_R2[vp][r]);
                uint4 tt = *(const uint4*)&s_T2[vp][t * 20 + 4 * j];
                uint4 fl = *(const uint4*)&s_f2[vp][0];
                unsigned f4u = s_f2[vp][4];
                h2 ff0 = u2h(fl.x), ff1 = u2h(fl.y), ff2v = u2h(fl.z),
                   ff3 = u2h(fl.w), ff4 = u2h(f4u);
                unsigned tk[4] = {tt.x, tt.y, tt.z, tt.w};
                #pragma unroll
                for (int kk = 0; kk < 4; ++kk) {
                    h2 e2 = rr * u2h(tk[kk]);               // v_pk_mul_f16
                    den[kk]    = FDOT2(e2, one2, den[kk]);
                    num[0][kk] = FDOT2(e2, ff0, num[0][kk]);
                    num[1][kk] = FDOT2(e2, ff1, num[1][kk]);
                    num[2][kk] = FDOT2(e2, ff2v, num[2][kk]);
                    num[3][kk] = FDOT2(e2, ff3, num[3][kk]);
                    num[4][kk] = FDOT2(e2, ff4, num[4][kk]);
                }
            }
            float seps = s_sre[r];
            #pragma unroll
            for (int kk = 0; kk < 4; ++kk) {
                float inv = __builtin_amdgcn_rcpf(den[kk] + seps);
                #pragma unroll
                for (int w = 0; w < W; ++w)
                    s_descT[w][j * 4 + kk][g] = f2bf(num[w][kk] * inv);
            }
        }
    } else {
        // ---- generic fallback (R4-proven): per-w gaussians ----
        float koff[4];
        #pragma unroll
        for (int kk = 0; kk < 4; ++kk) koff[kk] = (float)(j * 4 + kk) * kstep;
        #pragma unroll 1
        for (int w = 0; w < W; ++w) {
            const float mu_r = mu_rho[w * G + g];
            const float sr   = sig_rho[w * G + g];
            const float c_sr = NLOG2E / (sr * sr + EPSV);
            const float mu_t = mu_theta[w * G + g];
            const float st   = sig_theta[w * G + g];
            const float c_st = NLOG2E / (st * st + EPSV);
            float den[4] = {0.f, 0.f, 0.f, 0.f};
            float nm[4]  = {0.f, 0.f, 0.f, 0.f};
            for (int v = 0; v < V; ++v) {
                float fw  = s_pt[v][w];
                float rv  = s_pt[v][5];
                float mrk = s_pt[v][6];
                float th  = s_pt[v][7];
                float dr = rv - mu_r;
                float argr = fmaf(dr * dr, c_sr, mrk);
                #pragma unroll
                for (int kk = 0; kk < 4; ++kk) {
                    float x = th + koff[kk];
                    x = x - floorf(x * inv_two_pi) * two_pi;
                    float t = x - mu_t;
                    float e = __builtin_amdgcn_exp2f(fmaf(t * t, c_st, argr));
                    den[kk] += e;
                    nm[kk] = fmaf(e, fw, nm[kk]);
                }
            }
            #pragma unroll
            for (int kk = 0; kk < 4; ++kk)
                s_descT[w][j * 4 + kk][g] =
                    f2bf(nm[kk] * __builtin_amdgcn_rcpf(den[kk] + EPSV));
        }
    }

    __syncthreads();

    // ---- stage 3: MFMA  C[16k x 80o] = descT[w]^ * Wc[w], max over k ----
    {
        const int ww = tid >> 6;     // wave id = w (0..4)
        const int l  = tid & 63;
        bf16x8 afrag[3];
        #pragma unroll
        for (int ks = 0; ks < 3; ++ks)
            afrag[ks] = *(const bf16x8*)(&s_descT[ww][l & 15]
                                                [ks * 32 + ((l >> 4) << 3)]);
        #pragma unroll
        for (int nt = 0; nt < 5; ++nt) {
            f32x4 acc = {0.f, 0.f, 0.f, 0.f};
            #pragma unroll
            for (int ks = 0; ks < 3; ++ks) {
                const unsigned short* bp =
                    wsB + ((size_t)(((ww * 3 + ks) * 5 + nt) * 64 + l)) * 8;
                bf16x8 bfrag = *(const bf16x8*)bp;
                acc = __builtin_amdgcn_mfma_f32_16x16x32_bf16(
                          afrag[ks], bfrag, acc, 0, 0, 0);
            }
            float m1 = fmaxf(fmaxf(acc[0], acc[1]), fmaxf(acc[2], acc[3]));
            s_red[ww][l] = m1;
            float r0 = s_red[ww][l & 15];
            float r1 = s_red[ww][(l & 15) + 16];
            float r2 = s_red[ww][(l & 15) + 32];
            float r3 = s_red[ww][(l & 15) + 48];
            float mx = fmaxf(fmaxf(r0, r1), fmaxf(r2, r3));
            if (l < 16) {
                int oo = nt * 16 + l;
                out[p * (W * O) + ww * O + oo] = mx + bc[ww * O + oo];
            }
        }
    }
}

extern "C" void kernel_launch(void* const* d_in, const int* in_sizes, int n_in,
                              void* d_out, int out_size, void* d_ws, size_t ws_size,
                              hipStream_t stream) {
    const float* feat      = (const float*)d_in[0];
    const float* rho       = (const float*)d_in[1];
    const float* theta     = (const float*)d_in[2];
    const float* mask      = (const float*)d_in[3];
    const float* mu_rho    = (const float*)d_in[4];
    const float* mu_theta  = (const float*)d_in[5];
    const float* sig_rho   = (const float*)d_in[6];
    const float* sig_theta = (const float*)d_in[7];
    const float* Wc        = (const float*)d_in[8];
    const float* bc        = (const float*)d_in[9];
    float* outp            = (float*)d_out;

    const int np = in_sizes[1] / V;   // B*N points
    unsigned short* ws = (unsigned short*)d_ws;   // 75*64*8 shorts = 76.8 KB

    pack_wc_kernel<<<75, 64, 0, stream>>>(Wc, ws);
    conv_kernel<<<np, 320, 0, stream>>>(feat, rho, theta, mask, mu_rho, mu_theta,
                                        sig_rho, sig_theta, ws, bc, outp);
}

// Round 7
// 55.989 us; speedup vs baseline: 1.0925x; 1.0925x over previous
//
#include <hip/hip_runtime.h>

#define V 64
#define W 5
#define G 80
#define O 80
#define NROT 16
#define GPAD 96
#define EPSV 1e-5f
#define NLOG2E (-1.4426950408889634f)

#define TSTR 72           // 16-bit elems per row of T/A (144 B: 16B-aligned, bank-spread)
#define XSTR 68           // f32 per row of s_x/s_arg/s_fT (272 B rows, 16B-aligned)
#define DSTR 260          // f32 per row of s_den

using bf16x8 = __attribute__((ext_vector_type(8))) short;
using f32x4  = __attribute__((ext_vector_type(4))) float;

__device__ __forceinline__ unsigned short f2bf(float x) {
    unsigned u = __float_as_uint(x);
    unsigned r = (u + 0x7FFFu + ((u >> 16) & 1u)) >> 16;   // RNE
    return (unsigned short)r;
}

// ---- stage-2 MFMA element type: f16 if available (better precision), else bf16
#if __has_builtin(__builtin_amdgcn_mfma_f32_16x16x32_f16)
typedef _Float16 elem_t;
typedef elem_t efrag __attribute__((ext_vector_type(8)));
#define EMFMA(a, b, c) __builtin_amdgcn_mfma_f32_16x16x32_f16((a), (b), (c), 0, 0, 0)
__device__ __forceinline__ unsigned epack(float a, float b) {
    auto r = __builtin_amdgcn_cvt_pkrtz(a, b);
    return __builtin_bit_cast(unsigned, r);
}
#else
typedef short elem_t;
typedef elem_t efrag __attribute__((ext_vector_type(8)));
#define EMFMA(a, b, c) __builtin_amdgcn_mfma_f32_16x16x32_bf16((a), (b), (c), 0, 0, 0)
__device__ __forceinline__ unsigned epack(float a, float b) {
    return (unsigned)f2bf(a) | ((unsigned)f2bf(b) << 16);
}
#endif

// ============================================================================
// Pack Wc into bf16 B-frags for stage-3 mfma_f32_16x16x32_bf16 (R4-proven).
// ============================================================================
__global__ __launch_bounds__(64) void pack_wc_kernel(
    const float* __restrict__ Wc, unsigned short* __restrict__ wsB)
{
    const int f = blockIdx.x, l = threadIdx.x;
    const int w = f / 15, r = f % 15, ks = r / 5, nt = r % 5;
    const int g0 = ks * 32 + ((l >> 4) << 3);
    const int o  = nt * 16 + (l & 15);
    unsigned short v[8];
    #pragma unroll
    for (int i = 0; i < 8; ++i) {
        int g = g0 + i;
        v[i] = (g < G) ? f2bf(Wc[(w * G + g) * O + o]) : (unsigned short)0;
    }
    *(uint4*)(wsB + ((size_t)f * 64 + l) * 8) = *(const uint4*)v;
}

// ============================================================================
// Fused kernel: one block per point, 320 threads = 5 waves.
// Fast path: num[(w,r),(t,k)] = F''[32x64] x T[64x256] via MFMA.
// ============================================================================
__global__ __launch_bounds__(320) void conv_kernel(
    const float* __restrict__ feat,      // [NP][V][W]
    const float* __restrict__ rho,       // [NP][V]
    const float* __restrict__ theta,     // [NP][V]
    const float* __restrict__ mask,      // [NP][V]
    const float* __restrict__ mu_rho,    // [W][G]
    const float* __restrict__ mu_theta,  // [W][G]
    const float* __restrict__ sig_rho,   // [W][G]
    const float* __restrict__ sig_theta, // [W][G]
    const unsigned short* __restrict__ wsB,  // packed bf16 Wc B-frags
    const float* __restrict__ bc,        // [W][O]
    float* __restrict__ out)             // [NP][W][O]
{
    // s_big: T[256][TSTR] (16-bit) in phases 2-4; descT[5][16][96] bf16 after.
    __shared__ __align__(16) unsigned short s_big[256 * TSTR];     // 36864 B
    __shared__ __align__(16) unsigned short s_A[32 * TSTR];        //  4608 B
    __shared__ float s_fT[W][XSTR];                                //  1360 B
    __shared__ float s_x[NROT][XSTR];                              //  4352 B
    __shared__ float s_arg[5][XSTR];                               //  1360 B
    __shared__ float s_den[5][DSTR];                               //  5200 B
    __shared__ float s_red[5][64];                                 //  1280 B
    __shared__ float s_ct[16], s_mt[16], s_shift[8], s_sre[8];

    const int tid = threadIdx.x;
    const int p = blockIdx.x;
    const int g = tid % G;   // 0..79
    const int j = tid / G;   // 0..3

    const float kstep = 0.39269908169872414f;      // 2*pi/16
    const float two_pi = 6.283185307179586f;
    const float inv_two_pi = 0.15915494309189535f;

    // ---- phase 1: stage all point data (no internal deps) ----
    {
        int v = tid / 5, w = tid - 5 * (tid / 5);
        s_fT[w][v] = feat[p * V * W + tid];        // tid == v*5+w
    }
    {
        int r = tid >> 6, v = tid & 63;
        float mu_r = mu_rho[r * 16];
        float sr   = sig_rho[r * 16];
        float c_r  = NLOG2E / (sr * sr + EPSV);
        float rv   = rho[p * V + v];
        float mk   = (mask[p * V + v] != 0.0f) ? 0.0f : -1e30f;
        float dr = rv - mu_r;
        s_arg[r][v] = fmaf(dr * dr, c_r, mk);      // mask folded
    }
    if (tid < 16) {
        float st = sig_theta[tid];
        s_ct[tid] = NLOG2E / (st * st + EPSV);
        s_mt[tid] = mu_theta[tid];
    }
    for (int i = tid; i < V * NROT; i += 320) {
        int v = i >> 4, k = i & 15;
        float x = theta[p * V + v] + (float)k * kstep;
        x -= floorf(x * inv_two_pi) * two_pi;      // jnp.mod(x, 2pi)
        s_x[k][v] = x;
    }

    // uniformity + meshgrid check
    const int wchk = 1 + j;
    const int gr = (g >> 4) << 4;
    const int gt = g & 15;
    int pred = (mu_rho  [wchk * G + g] == mu_rho  [g]) &&
               (mu_theta[wchk * G + g] == mu_theta[g]) &&
               (sig_rho [wchk * G + g] == sig_rho [g]) &&
               (sig_theta[wchk * G + g] == sig_theta[g]) &&
               (mu_rho  [g] == mu_rho  [gr]) &&
               (sig_rho [g] == sig_rho [gr]) &&
               (mu_theta[g] == mu_theta[gt]) &&
               (sig_theta[g] == sig_theta[gt]);
    const int uni = __syncthreads_and(pred);       // block-uniform

    if (uni) {
        elem_t* Tl = (elem_t*)s_big;               // [256 rows (t,k)][TSTR v]

        // ---- phase 2: build T (16384 exps over block) + per-r shift ----
        for (int i = tid; i < 2048; i += 320) {
            int n = i >> 3, s = i & 7;             // row n=(t,k), v-seg s
            int t = n >> 4, k = n & 15;
            float ct = s_ct[t], mt = s_mt[t];
            const float* xp = &s_x[k][8 * s];
            float4 xa = *(const float4*)xp;
            float4 xb = *(const float4*)(xp + 4);
            float d0, d1;
            unsigned pk0, pk1, pk2, pk3;
            d0 = xa.x - mt; d1 = xa.y - mt;
            pk0 = epack(__builtin_amdgcn_exp2f(ct * d0 * d0),
                        __builtin_amdgcn_exp2f(ct * d1 * d1));
            d0 = xa.z - mt; d1 = xa.w - mt;
            pk1 = epack(__builtin_amdgcn_exp2f(ct * d0 * d0),
                        __builtin_amdgcn_exp2f(ct * d1 * d1));
            d0 = xb.x - mt; d1 = xb.y - mt;
            pk2 = epack(__builtin_amdgcn_exp2f(ct * d0 * d0),
                        __builtin_amdgcn_exp2f(ct * d1 * d1));
            d0 = xb.z - mt; d1 = xb.w - mt;
            pk3 = epack(__builtin_amdgcn_exp2f(ct * d0 * d0),
                        __builtin_amdgcn_exp2f(ct * d1 * d1));
            *(uint4*)(Tl + n * TSTR + 8 * s) = make_uint4(pk0, pk1, pk2, pk3);
        }
        if (tid < 5) {
            float m = -3.0e38f;
            #pragma unroll 8
            for (int v = 0; v < V; ++v) m = fmaxf(m, s_arg[tid][v]);
            float s = fminf(-m, 60.0f);            // arg <= 0 -> s >= 0
            s_shift[tid] = s;
            s_sre[tid]   = EPSV * __builtin_amdgcn_exp2f(s);
        }
        __syncthreads();

        // ---- phase 3: build F'' [32][64]: rows 0-24 f*R', 25-29 R', 30-31 zero
        if (tid < 256) {
            int m = tid >> 3, s = tid & 7;
            unsigned pk0 = 0, pk1 = 0, pk2 = 0, pk3 = 0;
            if (m < 30) {
                int w  = m / 5;
                int rr = (m < 25) ? (m - 5 * w) : (m - 25);
                float sh = s_shift[rr];
                const float* ap = &s_arg[rr][8 * s];
                float4 aa = *(const float4*)ap;
                float4 ab = *(const float4*)(ap + 4);
                float e0 = __builtin_amdgcn_exp2f(aa.x + sh);
                float e1 = __builtin_amdgcn_exp2f(aa.y + sh);
                float e2 = __builtin_amdgcn_exp2f(aa.z + sh);
                float e3 = __builtin_amdgcn_exp2f(aa.w + sh);
                float e4 = __builtin_amdgcn_exp2f(ab.x + sh);
                float e5 = __builtin_amdgcn_exp2f(ab.y + sh);
                float e6 = __builtin_amdgcn_exp2f(ab.z + sh);
                float e7 = __builtin_amdgcn_exp2f(ab.w + sh);
                if (m < 25) {
                    const float* fp = &s_fT[w][8 * s];
                    float4 fa = *(const float4*)fp;
                    float4 fb = *(const float4*)(fp + 4);
                    e0 *= fa.x; e1 *= fa.y; e2 *= fa.z; e3 *= fa.w;
                    e4 *= fb.x; e5 *= fb.y; e6 *= fb.z; e7 *= fb.w;
                }
                pk0 = epack(e0, e1); pk1 = epack(e2, e3);
                pk2 = epack(e4, e5); pk3 = epack(e6, e7);
            }
            *(uint4*)((elem_t*)s_A + m * TSTR + 8 * s) =
                make_uint4(pk0, pk1, pk2, pk3);
        }
        __syncthreads();

        // ---- phase 4: stage-2 MFMA: C[32 x 256] = F'' x T ----
        const int ww = tid >> 6;     // wave 0..4
        const int l  = tid & 63;
        const int lg = l >> 4, lc = l & 15;
        const elem_t* EA = (const elem_t*)s_A;
        efrag a00 = *(const efrag*)(EA + lc * TSTR + (lg << 3));
        efrag a01 = *(const efrag*)(EA + lc * TSTR + 32 + (lg << 3));
        efrag a10 = *(const efrag*)(EA + (16 + lc) * TSTR + (lg << 3));
        efrag a11 = *(const efrag*)(EA + (16 + lc) * TSTR + 32 + (lg << 3));
        f32x4 acc0[4], acc1[4];
        #pragma unroll
        for (int q = 0; q < 4; ++q) {
            int nt = ww + 5 * q;
            if (nt < 16) {
                const elem_t* bp = Tl + (nt * 16 + lc) * TSTR;
                efrag b0 = *(const efrag*)(bp + (lg << 3));
                efrag b1 = *(const efrag*)(bp + 32 + (lg << 3));
                f32x4 z = {0.f, 0.f, 0.f, 0.f};
                f32x4 c0 = EMFMA(a00, b0, z);
                c0 = EMFMA(a01, b1, c0);
                f32x4 c1 = EMFMA(a10, b0, z);
                c1 = EMFMA(a11, b1, c1);
                acc0[q] = c0; acc1[q] = c1;
                int n = nt * 16 + lc;
                if (lg == 2) {                    // rows 25,26,27 -> den r=0,1,2
                    s_den[0][n] = c1[1]; s_den[1][n] = c1[2]; s_den[2][n] = c1[3];
                } else if (lg == 3) {             // rows 28,29 -> den r=3,4
                    s_den[3][n] = c1[0]; s_den[4][n] = c1[1];
                }
            }
        }
        __syncthreads();   // den complete; T now dead -> descT may overlay

        // ---- phase 5: normalize -> bf16 descT[w][k][g], g = r*16 + t ----
        unsigned short* descT = s_big;
        int w0[4], r0[4], w1[4], r1[4];
        bool ok1[4];
        #pragma unroll
        for (int i = 0; i < 4; ++i) {
            int m = lg * 4 + i;
            w0[i] = m / 5; r0[i] = m - 5 * w0[i];
            int m2 = 16 + lg * 4 + i;
            ok1[i] = (m2 < 25);
            int mm = ok1[i] ? m2 : 24;
            w1[i] = mm / 5; r1[i] = mm - 5 * w1[i];
        }
        #pragma unroll
        for (int q = 0; q < 4; ++q) {
            int nt = ww + 5 * q;
            if (nt < 16) {
                int n = nt * 16 + lc;             // t = nt, k = lc
                #pragma unroll
                for (int i = 0; i < 4; ++i) {
                    float den = s_den[r0[i]][n] + s_sre[r0[i]];
                    float val = acc0[q][i] * __builtin_amdgcn_rcpf(den);
                    descT[(w0[i] * 16 + lc) * GPAD + r0[i] * 16 + nt] = f2bf(val);
                }
                #pragma unroll
                for (int i = 0; i < 4; ++i) {
                    if (ok1[i]) {
                        float den = s_den[r1[i]][n] + s_sre[r1[i]];
                        float val = acc1[q][i] * __builtin_amdgcn_rcpf(den);
                        descT[(w1[i] * 16 + lc) * GPAD + r1[i] * 16 + nt] = f2bf(val);
                    }
                }
            }
        }
    } else {
        // ---- generic fallback: per-w gaussians (correctness path) ----
        unsigned short* descT = s_big;
        #pragma unroll 1
        for (int w = 0; w < W; ++w) {
            const float mu_r = mu_rho[w * G + g];
            const float sr   = sig_rho[w * G + g];
            const float c_sr = NLOG2E / (sr * sr + EPSV);
            const float mu_t = mu_theta[w * G + g];
            const float st   = sig_theta[w * G + g];
            const float c_st = NLOG2E / (st * st + EPSV);
            float den[4] = {0.f, 0.f, 0.f, 0.f};
            float nm[4]  = {0.f, 0.f, 0.f, 0.f};
            for (int v = 0; v < V; ++v) {
                float rv  = rho[p * V + v];
                float mk  = (mask[p * V + v] != 0.0f) ? 0.0f : -1e30f;
                float fw  = s_fT[w][v];
                float dr = rv - mu_r;
                float argr = fmaf(dr * dr, c_sr, mk);
                #pragma unroll
                for (int kk = 0; kk < 4; ++kk) {
                    float x = s_x[4 * j + kk][v];
                    float t = x - mu_t;
                    float e = __builtin_amdgcn_exp2f(fmaf(t * t, c_st, argr));
                    den[kk] += e;
                    nm[kk] = fmaf(e, fw, nm[kk]);
                }
            }
            #pragma unroll
            for (int kk = 0; kk < 4; ++kk)
                descT[(w * 16 + 4 * j + kk) * GPAD + g] =
                    f2bf(nm[kk] * __builtin_amdgcn_rcpf(den[kk] + EPSV));
        }
    }

    // ---- common: zero descT g-pad (cols 80..95) ----
    {
        unsigned* d32 = (unsigned*)s_big;
        for (int i = tid; i < W * NROT * 8; i += 320)
            d32[(i >> 3) * 48 + 40 + (i & 7)] = 0u;
    }
    __syncthreads();

    // ---- phase 6: stage-3 MFMA (R4-proven): out = max_k descT x Wc + bc ----
    {
        const unsigned short* descT = s_big;
        const int ww = tid >> 6;
        const int l  = tid & 63;
        bf16x8 afrag[3];
        #pragma unroll
        for (int ks = 0; ks < 3; ++ks)
            afrag[ks] = *(const bf16x8*)(descT + (ww * 16 + (l & 15)) * GPAD +
                                         ks * 32 + ((l >> 4) << 3));
        #pragma unroll
        for (int nt = 0; nt < 5; ++nt) {
            f32x4 acc = {0.f, 0.f, 0.f, 0.f};
            #pragma unroll
            for (int ks = 0; ks < 3; ++ks) {
                const unsigned short* bp =
                    wsB + ((size_t)(((ww * 3 + ks) * 5 + nt) * 64 + l)) * 8;
                bf16x8 bfrag = *(const bf16x8*)bp;
                acc = __builtin_amdgcn_mfma_f32_16x16x32_bf16(
                          afrag[ks], bfrag, acc, 0, 0, 0);
            }
            float m1 = fmaxf(fmaxf(acc[0], acc[1]), fmaxf(acc[2], acc[3]));
            s_red[ww][l] = m1;
            float r0 = s_red[ww][l & 15];
            float r1 = s_red[ww][(l & 15) + 16];
            float r2 = s_red[ww][(l & 15) + 32];
            float r3 = s_red[ww][(l & 15) + 48];
            float mx = fmaxf(fmaxf(r0, r1), fmaxf(r2, r3));
            if (l < 16) {
                int oo = nt * 16 + l;
                out[p * (W * O) + ww * O + oo] = mx + bc[ww * O + oo];
            }
        }
    }
}

extern "C" void kernel_launch(void* const* d_in, const int* in_sizes, int n_in,
                              void* d_out, int out_size, void* d_ws, size_t ws_size,
                              hipStream_t stream) {
    const float* feat      = (const float*)d_in[0];
    const float* rho       = (const float*)d_in[1];
    const float* theta     = (const float*)d_in[2];
    const float* mask      = (const float*)d_in[3];
    const float* mu_rho    = (const float*)d_in[4];
    const float* mu_theta  = (const float*)d_in[5];
    const float* sig_rho   = (const float*)d_in[6];
    const float* sig_theta = (const float*)d_in[7];
    const float* Wc        = (const float*)d_in[8];
    const float* bc        = (const float*)d_in[9];
    float* outp            = (float*)d_out;

    const int np = in_sizes[1] / V;   // B*N points
    unsigned short* ws = (unsigned short*)d_ws;   // 75*64*8 shorts = 76.8 KB

    pack_wc_kernel<<<75, 64, 0, stream>>>(Wc, ws);
    conv_kernel<<<np, 320, 0, stream>>>(feat, rho, theta, mask, mu_rho, mu_theta,
                                        sig_rho, sig_theta, ws, bc, outp);
}

// Round 8
// 23.423 us; speedup vs baseline: 2.6115x; 2.3903x over previous
//
#include <hip/hip_runtime.h>

#define V 64
#define W 5
#define G 80
#define O 80
#define NROT 16
#define GPAD 104          // shorts per descT row (208 B: 16B-aligned, 2-way banks)
#define EPSV 1e-5f
#define NLOG2E (-1.4426950408889634f)

#define TSTR 72           // shorts per s_A row (144 B)
#define XSTR 68           // f32 per row of s_x/s_arg/s_fT (272 B)

using bf16x8 = __attribute__((ext_vector_type(8))) short;
using f32x4  = __attribute__((ext_vector_type(4))) float;

__device__ __forceinline__ unsigned short f2bf(float x) {
    unsigned u = __float_as_uint(x);
    unsigned r = (u + 0x7FFFu + ((u >> 16) & 1u)) >> 16;   // RNE
    return (unsigned short)r;
}
__device__ __forceinline__ float pick5(float a0, float a1, float a2,
                                       float a3, float a4, int r) {
    float x = (r == 1) ? a1 : a0;
    x = (r == 2) ? a2 : x;
    x = (r == 3) ? a3 : x;
    x = (r == 4) ? a4 : x;
    return x;
}

// ---- stage-2 MFMA element type: f16 if available, else bf16 ----
#if __has_builtin(__builtin_amdgcn_mfma_f32_16x16x32_f16)
typedef _Float16 elem_t;
typedef elem_t efrag __attribute__((ext_vector_type(8)));
#define EMFMA(a, b, c) __builtin_amdgcn_mfma_f32_16x16x32_f16((a), (b), (c), 0, 0, 0)
__device__ __forceinline__ unsigned epack(float a, float b) {
    auto r = __builtin_amdgcn_cvt_pkrtz(a, b);
    return __builtin_bit_cast(unsigned, r);
}
#else
typedef short elem_t;
typedef elem_t efrag __attribute__((ext_vector_type(8)));
#define EMFMA(a, b, c) __builtin_amdgcn_mfma_f32_16x16x32_bf16((a), (b), (c), 0, 0, 0)
__device__ __forceinline__ unsigned epack(float a, float b) {
    return (unsigned)f2bf(a) | ((unsigned)f2bf(b) << 16);
}
#endif

// ============================================================================
// Pack Wc into bf16 B-frags for stage-3 mfma_f32_16x16x32_bf16 (R4-proven).
// ============================================================================
__global__ __launch_bounds__(64) void pack_wc_kernel(
    const float* __restrict__ Wc, unsigned short* __restrict__ wsB)
{
    const int f = blockIdx.x, l = threadIdx.x;
    const int w = f / 15, r = f % 15, ks = r / 5, nt = r % 5;
    const int g0 = ks * 32 + ((l >> 4) << 3);
    const int o  = nt * 16 + (l & 15);
    unsigned short v[8];
    #pragma unroll
    for (int i = 0; i < 8; ++i) {
        int g = g0 + i;
        v[i] = (g < G) ? f2bf(Wc[(w * G + g) * O + o]) : (unsigned short)0;
    }
    *(uint4*)(wsB + ((size_t)f * 64 + l) * 8) = *(const uint4*)v;
}

// ============================================================================
// Fused kernel: one block per point, 320 threads = 5 waves.
// Fast path: C[32 x 256] = F''[32x64] x T[64x256]; T computed IN-REGISTER
// per consuming lane (no LDS staging); dens extracted via __shfl.
// ============================================================================
__global__ __launch_bounds__(320, 5) void conv_kernel(
    const float* __restrict__ feat,      // [NP][V][W]
    const float* __restrict__ rho,       // [NP][V]
    const float* __restrict__ theta,     // [NP][V]
    const float* __restrict__ mask,      // [NP][V]
    const float* __restrict__ mu_rho,    // [W][G]
    const float* __restrict__ mu_theta,  // [W][G]
    const float* __restrict__ sig_rho,   // [W][G]
    const float* __restrict__ sig_theta, // [W][G]
    const unsigned short* __restrict__ wsB,  // packed bf16 Wc B-frags
    const float* __restrict__ bc,        // [W][O]
    float* __restrict__ out)             // [NP][W][O]
{
    __shared__ __align__(16) float s_x[NROT][XSTR];            // 4352 B
    __shared__ __align__(16) float s_fT[W][XSTR];              // 1360 B
    __shared__ __align__(16) float s_arg[5][XSTR];             // 1360 B
    __shared__ __align__(16) unsigned short s_A[32 * TSTR];    // 4608 B
    __shared__ __align__(16) unsigned short s_descT[W * NROT * GPAD]; // 16640 B
    __shared__ float s_red[5][64];                             // 1280 B
    __shared__ float s_ct[16], s_mt[16], s_sre[8];

    const int tid = threadIdx.x;
    const int p = blockIdx.x;
    const int g = tid % G;   // 0..79
    const int j = tid / G;   // 0..3

    const float kstep = 0.39269908169872414f;      // 2*pi/16
    const float two_pi = 6.283185307179586f;
    const float inv_two_pi = 0.15915494309189535f;

    // ---- phase 1: stage all point data (no internal deps) ----
    {
        int v = tid / 5, w = tid - 5 * (tid / 5);
        s_fT[w][v] = feat[p * V * W + tid];        // tid == v*5+w
    }
    {
        int r = tid >> 6, v = tid & 63;
        float mu_r = mu_rho[r * 16];
        float sr   = sig_rho[r * 16];
        float c_r  = NLOG2E / (sr * sr + EPSV);
        float rv   = rho[p * V + v];
        float mk   = (mask[p * V + v] != 0.0f) ? 0.0f : -1e30f;
        float dr = rv - mu_r;
        s_arg[r][v] = fmaf(dr * dr, c_r, mk);      // mask folded
    }
    if (tid < 16) {
        float st = sig_theta[tid];
        s_ct[tid] = NLOG2E / (st * st + EPSV);
        s_mt[tid] = mu_theta[tid];
    }
    for (int i = tid; i < V * NROT; i += 320) {
        int v = i >> 4, k = i & 15;
        float x = theta[p * V + v] + (float)k * kstep;
        x -= floorf(x * inv_two_pi) * two_pi;      // jnp.mod(x, 2pi)
        s_x[k][v] = x;
    }

    // uniformity + meshgrid check
    const int wchk = 1 + j;
    const int gr = (g >> 4) << 4;
    const int gt = g & 15;
    int pred = (mu_rho  [wchk * G + g] == mu_rho  [g]) &&
               (mu_theta[wchk * G + g] == mu_theta[g]) &&
               (sig_rho [wchk * G + g] == sig_rho [g]) &&
               (sig_theta[wchk * G + g] == sig_theta[g]) &&
               (mu_rho  [g] == mu_rho  [gr]) &&
               (sig_rho [g] == sig_rho [gr]) &&
               (mu_theta[g] == mu_theta[gt]) &&
               (sig_theta[g] == sig_theta[gt]);
    const int uni = __syncthreads_and(pred);       // block-uniform

    if (uni) {
        // ---- phase 2: F'' build (tid<256) || shift/sre (tid 256..260) ----
        if (tid < 256) {
            int m = tid >> 3, s = tid & 7;
            unsigned pk0 = 0, pk1 = 0, pk2 = 0, pk3 = 0;
            if (m < 30) {
                int w  = m / 5;
                int rr = (m < 25) ? (m - 5 * w) : (m - 25);
                float mx = -3.0e38f;               // inline per-row shift scan
                #pragma unroll
                for (int vs = 0; vs < 16; ++vs) {
                    float4 a = *(const float4*)&s_arg[rr][4 * vs];
                    mx = fmaxf(mx, fmaxf(fmaxf(a.x, a.y), fmaxf(a.z, a.w)));
                }
                float sh = fminf(-mx, 60.0f);
                const float* ap = &s_arg[rr][8 * s];
                float4 aa = *(const float4*)ap;
                float4 ab = *(const float4*)(ap + 4);
                float e0 = __builtin_amdgcn_exp2f(aa.x + sh);
                float e1 = __builtin_amdgcn_exp2f(aa.y + sh);
                float e2 = __builtin_amdgcn_exp2f(aa.z + sh);
                float e3 = __builtin_amdgcn_exp2f(aa.w + sh);
                float e4 = __builtin_amdgcn_exp2f(ab.x + sh);
                float e5 = __builtin_amdgcn_exp2f(ab.y + sh);
                float e6 = __builtin_amdgcn_exp2f(ab.z + sh);
                float e7 = __builtin_amdgcn_exp2f(ab.w + sh);
                if (m < 25) {
                    const float* fp = &s_fT[w][8 * s];
                    float4 fa = *(const float4*)fp;
                    float4 fb = *(const float4*)(fp + 4);
                    e0 *= fa.x; e1 *= fa.y; e2 *= fa.z; e3 *= fa.w;
                    e4 *= fb.x; e5 *= fb.y; e6 *= fb.z; e7 *= fb.w;
                }
                pk0 = epack(e0, e1); pk1 = epack(e2, e3);
                pk2 = epack(e4, e5); pk3 = epack(e6, e7);
            }
            *(uint4*)((elem_t*)s_A + m * TSTR + 8 * s) =
                make_uint4(pk0, pk1, pk2, pk3);
        } else if (tid < 261) {
            int r = tid - 256;
            float mx = -3.0e38f;
            #pragma unroll
            for (int vs = 0; vs < 16; ++vs) {
                float4 a = *(const float4*)&s_arg[r][4 * vs];
                mx = fmaxf(mx, fmaxf(fmaxf(a.x, a.y), fmaxf(a.z, a.w)));
            }
            float sh = fminf(-mx, 60.0f);
            s_sre[r] = EPSV * __builtin_amdgcn_exp2f(sh);
        }
        __syncthreads();

        // ---- phase 3: MFMA + in-register T + shfl-den + normalize ----
        const int ww = tid >> 6;     // wave 0..4
        const int l  = tid & 63;
        const int lg = l >> 4, lc = l & 15;
        const elem_t* EA = (const elem_t*)s_A;
        efrag a00 = *(const efrag*)(EA + lc * TSTR + (lg << 3));
        efrag a01 = *(const efrag*)(EA + lc * TSTR + 32 + (lg << 3));
        efrag a10 = *(const efrag*)(EA + (16 + lc) * TSTR + (lg << 3));
        efrag a11 = *(const efrag*)(EA + (16 + lc) * TSTR + 32 + (lg << 3));
        const float sre0 = s_sre[0], sre1 = s_sre[1], sre2 = s_sre[2],
                    sre3 = s_sre[3], sre4 = s_sre[4];

        int w0[4], r0[4], w1[4], r1[4];
        bool ok1[4];
        #pragma unroll
        for (int i = 0; i < 4; ++i) {
            int m = lg * 4 + i;
            w0[i] = m / 5; r0[i] = m - 5 * w0[i];
            int m2 = 16 + lg * 4 + i;
            ok1[i] = (m2 < 25);
            int mm = ok1[i] ? m2 : 24;
            w1[i] = mm / 5; r1[i] = mm - 5 * w1[i];
        }

        #pragma unroll
        for (int q = 0; q < 4; ++q) {
            int nt = ww + 5 * q;                   // wave-uniform
            if (nt < 16) {
                float ct = s_ct[nt], mt = s_mt[nt];
                const float* xr = &s_x[lc][lg << 3];
                float4 xa = *(const float4*)(xr);
                float4 xb = *(const float4*)(xr + 4);
                float4 xc = *(const float4*)(xr + 32);
                float4 xd = *(const float4*)(xr + 36);
                float d;
                #define EX(v) (d = (v) - mt, __builtin_amdgcn_exp2f(ct * d * d))
                unsigned u0 = epack(EX(xa.x), EX(xa.y));
                unsigned u1 = epack(EX(xa.z), EX(xa.w));
                unsigned u2 = epack(EX(xb.x), EX(xb.y));
                unsigned u3 = epack(EX(xb.z), EX(xb.w));
                efrag b0 = __builtin_bit_cast(efrag, make_uint4(u0, u1, u2, u3));
                u0 = epack(EX(xc.x), EX(xc.y));
                u1 = epack(EX(xc.z), EX(xc.w));
                u2 = epack(EX(xd.x), EX(xd.y));
                u3 = epack(EX(xd.z), EX(xd.w));
                efrag b1 = __builtin_bit_cast(efrag, make_uint4(u0, u1, u2, u3));
                #undef EX

                f32x4 z = {0.f, 0.f, 0.f, 0.f};
                f32x4 c0 = EMFMA(a00, b0, z);
                c0 = EMFMA(a01, b1, c0);
                f32x4 c1 = EMFMA(a10, b0, z);
                c1 = EMFMA(a11, b1, c1);

                // dens (F'' rows 25..29) live in lanes 32+lc / 48+lc
                float dn0 = __shfl(c1[1], 32 + lc);
                float dn1 = __shfl(c1[2], 32 + lc);
                float dn2 = __shfl(c1[3], 32 + lc);
                float dn3 = __shfl(c1[0], 48 + lc);
                float dn4 = __shfl(c1[1], 48 + lc);
                float i0 = __builtin_amdgcn_rcpf(dn0 + sre0);
                float i1 = __builtin_amdgcn_rcpf(dn1 + sre1);
                float i2 = __builtin_amdgcn_rcpf(dn2 + sre2);
                float i3 = __builtin_amdgcn_rcpf(dn3 + sre3);
                float i4 = __builtin_amdgcn_rcpf(dn4 + sre4);

                #pragma unroll
                for (int i = 0; i < 4; ++i) {
                    float inv = pick5(i0, i1, i2, i3, i4, r0[i]);
                    s_descT[(w0[i] * 16 + lc) * GPAD + r0[i] * 16 + nt] =
                        f2bf(c0[i] * inv);
                }
                #pragma unroll
                for (int i = 0; i < 4; ++i) {
                    if (ok1[i]) {
                        float inv = pick5(i0, i1, i2, i3, i4, r1[i]);
                        s_descT[(w1[i] * 16 + lc) * GPAD + r1[i] * 16 + nt] =
                            f2bf(c1[i] * inv);
                    }
                }
            }
        }
    } else {
        // ---- generic fallback: per-w gaussians (correctness path) ----
        #pragma unroll 1
        for (int w = 0; w < W; ++w) {
            const float mu_r = mu_rho[w * G + g];
            const float sr   = sig_rho[w * G + g];
            const float c_sr = NLOG2E / (sr * sr + EPSV);
            const float mu_t = mu_theta[w * G + g];
            const float st   = sig_theta[w * G + g];
            const float c_st = NLOG2E / (st * st + EPSV);
            float den[4] = {0.f, 0.f, 0.f, 0.f};
            float nm[4]  = {0.f, 0.f, 0.f, 0.f};
            for (int v = 0; v < V; ++v) {
                float rv  = rho[p * V + v];
                float mk  = (mask[p * V + v] != 0.0f) ? 0.0f : -1e30f;
                float fw  = s_fT[w][v];
                float dr = rv - mu_r;
                float argr = fmaf(dr * dr, c_sr, mk);
                #pragma unroll
                for (int kk = 0; kk < 4; ++kk) {
                    float x = s_x[4 * j + kk][v];
                    float t = x - mu_t;
                    float e = __builtin_amdgcn_exp2f(fmaf(t * t, c_st, argr));
                    den[kk] += e;
                    nm[kk] = fmaf(e, fw, nm[kk]);
                }
            }
            #pragma unroll
            for (int kk = 0; kk < 4; ++kk)
                s_descT[(w * 16 + 4 * j + kk) * GPAD + g] =
                    f2bf(nm[kk] * __builtin_amdgcn_rcpf(den[kk] + EPSV));
        }
    }

    // ---- common: zero descT g-pad (cols 80..103 = u32 cols 40..51) ----
    {
        unsigned* d32 = (unsigned*)s_descT;
        for (int i = tid; i < 80 * 12; i += 320)
            d32[(i / 12) * (GPAD / 2) + 40 + (i % 12)] = 0u;
    }
    __syncthreads();

    // ---- phase 4: stage-3 MFMA (R4-proven): out = max_k descT x Wc + bc ----
    {
        const int ww = tid >> 6;
        const int l  = tid & 63;
        bf16x8 afrag[3];
        #pragma unroll
        for (int ks = 0; ks < 3; ++ks)
            afrag[ks] = *(const bf16x8*)(s_descT + (ww * 16 + (l & 15)) * GPAD +
                                         ks * 32 + ((l >> 4) << 3));
        #pragma unroll
        for (int nt = 0; nt < 5; ++nt) {
            f32x4 acc = {0.f, 0.f, 0.f, 0.f};
            #pragma unroll
            for (int ks = 0; ks < 3; ++ks) {
                const unsigned short* bp =
                    wsB + ((size_t)(((ww * 3 + ks) * 5 + nt) * 64 + l)) * 8;
                bf16x8 bfrag = *(const bf16x8*)bp;
                acc = __builtin_amdgcn_mfma_f32_16x16x32_bf16(
                          afrag[ks], bfrag, acc, 0, 0, 0);
            }
            float m1 = fmaxf(fmaxf(acc[0], acc[1]), fmaxf(acc[2], acc[3]));
            s_red[ww][l] = m1;
            float r0 = s_red[ww][l & 15];
            float r1 = s_red[ww][(l & 15) + 16];
            float r2 = s_red[ww][(l & 15) + 32];
            float r3 = s_red[ww][(l & 15) + 48];
            float mx = fmaxf(fmaxf(r0, r1), fmaxf(r2, r3));
            if (l < 16) {
                int oo = nt * 16 + l;
                out[p * (W * O) + ww * O + oo] = mx + bc[ww * O + oo];
            }
        }
    }
}

extern "C" void kernel_launch(void* const* d_in, const int* in_sizes, int n_in,
                              void* d_out, int out_size, void* d_ws, size_t ws_size,
                              hipStream_t stream) {
    const float* feat      = (const float*)d_in[0];
    const float* rho       = (const float*)d_in[1];
    const float* theta     = (const float*)d_in[2];
    const float* mask      = (const float*)d_in[3];
    const float* mu_rho    = (const float*)d_in[4];
    const float* mu_theta  = (const float*)d_in[5];
    const float* sig_rho   = (const float*)d_in[6];
    const float* sig_theta = (const float*)d_in[7];
    const float* Wc        = (const float*)d_in[8];
    const float* bc        = (const float*)d_in[9];
    float* outp            = (float*)d_out;

    const int np = in_sizes[1] / V;   // B*N points
    unsigned short* ws = (unsigned short*)d_ws;   // 75*64*8 shorts = 76.8 KB

    pack_wc_kernel<<<75, 64, 0, stream>>>(Wc, ws);
    conv_kernel<<<np, 320, 0, stream>>>(feat, rho, theta, mask, mu_rho, mu_theta,
                                        sig_rho, sig_theta, ws, bc, outp);
}